// Round 3
// baseline (2270.716 us; speedup 1.0000x reference)
//
#include <hip/hip_runtime.h>
#include <math.h>

#define NB 1024
#define NT 64
#define NH 512
#define NE 200000
#define LN_EPS 1e-5f

typedef __bf16 bf16;
typedef __attribute__((ext_vector_type(8))) __bf16 bf16x8;
typedef __attribute__((ext_vector_type(4))) float f32x4;

// ---------------- LayerNorm block statistics (256 threads, 512 elems) -------
__device__ __forceinline__ void ln_stats(float sum, float sq, float& mean, float& rstd) {
#pragma unroll
  for (int o = 32; o > 0; o >>= 1) {
    sum += __shfl_down(sum, o);
    sq  += __shfl_down(sq, o);
  }
  __shared__ float red[8];
  const int wid = threadIdx.x >> 6;
  if ((threadIdx.x & 63) == 0) { red[wid * 2] = sum; red[wid * 2 + 1] = sq; }
  __syncthreads();
  if (threadIdx.x == 0) {
    const float ts = red[0] + red[2] + red[4] + red[6];
    const float tq = red[1] + red[3] + red[5] + red[7];
    const float m  = ts * (1.0f / NH);
    const float var = tq * (1.0f / NH) - m * m;
    red[0] = m;
    red[1] = rsqrtf(var + LN_EPS);
  }
  __syncthreads();
  mean = red[0];
  rstd = red[1];
}

__device__ __forceinline__ float sigmoid_f(float x) {
  return 1.0f / (1.0f + __expf(-x));
}
__device__ __forceinline__ float tanh_f(float x) {
  x = fminf(fmaxf(x, -15.0f), 15.0f);
  const float e = __expf(2.0f * x);
  return (e - 1.0f) / (e + 1.0f);
}

// ---------------- active mask, transposed [T][B] ----------------------------
__global__ void active_kernel(const int* __restrict__ actions,
                              const int* __restrict__ stopidx,
                              int* __restrict__ mask_T) {
  const int b = blockIdx.x * blockDim.x + threadIdx.x;
  if (b >= NB) return;
  const int si = stopidx[b];
  bool done = false;
  for (int t = 0; t < NT; ++t) {
    const int a = actions[b * NT + t];
    const bool is_stop = (a == si) || (a < 0);
    mask_T[t * NB + b] = (!done && !is_stop) ? 1 : 0;
    done = done || is_stop;
  }
}

// ---------------- weights fp32 -> bf16 --------------------------------------
__global__ void wcvt_kernel(const float* __restrict__ wih,
                            const float* __restrict__ whh,
                            bf16* __restrict__ wihb, bf16* __restrict__ whhb) {
  const int i = (blockIdx.x * 256 + threadIdx.x) * 4;
  const float4 a = *(const float4*)&wih[i];
  const float4 b = *(const float4*)&whh[i];
  union { bf16 h[4]; uint2 u; } pa, pb;
  pa.h[0] = (bf16)a.x; pa.h[1] = (bf16)a.y; pa.h[2] = (bf16)a.z; pa.h[3] = (bf16)a.w;
  pb.h[0] = (bf16)b.x; pb.h[1] = (bf16)b.y; pb.h[2] = (bf16)b.z; pb.h[3] = (bf16)b.w;
  *(uint2*)&wihb[i] = pa.u;
  *(uint2*)&whhb[i] = pb.u;
}

// ---------------- gather edge rows -> bf16 X[t][b][H] -----------------------
__global__ void xall_kernel(const int* __restrict__ actions,
                            const float* __restrict__ edges,
                            bf16* __restrict__ xbf) {
  const int blk = blockIdx.x;       // = b*NT + t
  const int b = blk >> 6, t = blk & 63;
  int a = actions[blk];
  a = min(max(a, 0), NE - 1);
  const int i = threadIdx.x * 2;
  const float2 v = *(const float2*)&edges[(size_t)a * NH + i];
  union { bf16 h[2]; unsigned u; } p;
  p.h[0] = (bf16)v.x; p.h[1] = (bf16)v.y;
  *(unsigned*)&xbf[((size_t)t * NB + b) * NH + i] = p.u;
}

// ---------------- h0 = LN(question + segment_mean(node_tokens)) -------------
__global__ void h0_kernel(const float* __restrict__ q,
                          const float* __restrict__ nodes,
                          const int* __restrict__ locals,
                          const int* __restrict__ ptr,
                          const float* __restrict__ lnw,
                          const float* __restrict__ lnb,
                          float* __restrict__ h0, bf16* __restrict__ h0b) {
  const int b = blockIdx.x;
  const int i = threadIdx.x * 2;
  const int p0 = ptr[b], p1 = ptr[b + 1];
  const float denom = fmaxf((float)(p1 - p0), 1.0f);
  float s0 = 0.f, s1 = 0.f;
  for (int p = p0; p < p1; ++p) {
    const int node = locals[p];
    const float2 nv = *(const float2*)&nodes[(size_t)node * NH + i];
    s0 += nv.x; s1 += nv.y;
  }
  const float2 qv = *(const float2*)&q[(size_t)b * NH + i];
  const float v0 = qv.x + s0 / denom;
  const float v1 = qv.y + s1 / denom;
  float mean, rstd;
  ln_stats(v0 + v1, v0 * v0 + v1 * v1, mean, rstd);
  const float2 lw = *(const float2*)&lnw[i];
  const float2 lb = *(const float2*)&lnb[i];
  float2 o;
  o.x = (v0 - mean) * rstd * lw.x + lb.x;
  o.y = (v1 - mean) * rstd * lw.y + lb.y;
  *(float2*)&h0[(size_t)b * NH + i] = o;
  union { bf16 h[2]; unsigned u; } p;
  p.h[0] = (bf16)o.x; p.h[1] = (bf16)o.y;
  *(unsigned*)&h0b[(size_t)b * NH + i] = p.u;
}

// ---------------- persistent GRU: all 63 steps, on-device barriers ----------
// Grid 256 = 32 c-tiles x 8 b-tiles (b-tile = blk&7 -> XCD-local under
// round-robin; correctness does not depend on it). Block: 512 thr = 8 waves
// = 4 m-strips(32 rows) x 2 k-halves(256). Weights LDS-resident.
#define MFMA_BF16 __builtin_amdgcn_mfma_f32_16x16x32_bf16
__global__ __launch_bounds__(512, 2) void pers_kernel(
    float* __restrict__ hstates,        // [NT][NB][NH] fp32, slot 0 pre-filled
    bf16* __restrict__ hbf0, bf16* __restrict__ hbf1,  // ping-pong [NB][NH]
    const bf16* __restrict__ xbf,       // [NT][NB][NH]
    const bf16* __restrict__ wihb, const bf16* __restrict__ whhb,
    const float* __restrict__ b_ih, const float* __restrict__ b_hh,
    const int* __restrict__ mask_T,     // [NT][NB]
    int* __restrict__ cnt) {            // [8], zeroed
  __shared__ bf16 Wi[48][520];          // rows: gate*16 + n, +8 pad (2-way ok)
  __shared__ bf16 Wh[48][520];
  __shared__ float red[8][4][64][4];    // [frag][mw][lane][4] k-reduce buffer

  const int tid = threadIdx.x;
  const int blk = blockIdx.x;
  const int btile = blk & 7;
  const int ctile = blk >> 3;
  const int b0 = btile * 128;
  const int c0 = ctile * 16;

  // ---- load weight tiles to LDS once ----
  for (int i = tid; i < 48 * 64; i += 512) {
    const int row = i >> 6, ch = (i & 63) * 8;
    const int g = row >> 4, n = row & 15;
    const size_t src = ((size_t)(g * NH + c0 + n)) * NH + ch;
    *(int4*)&Wi[row][ch] = *(const int4*)&wihb[src];
    *(int4*)&Wh[row][ch] = *(const int4*)&whhb[src];
  }
  __syncthreads();

  const int wave = tid >> 6, lane = tid & 63;
  const int ln15 = lane & 15, q8 = (lane >> 4) * 8;
  const int mw = wave & 3, kw = wave >> 2;
  const int mbase = b0 + mw * 32;
  const int k0 = kw * 256;

  const int c = c0 + ln15;
  const float bR = b_ih[c] + b_hh[c];
  const float bZ = b_ih[NH + c] + b_hh[NH + c];
  const float bI = b_ih[2 * NH + c];
  const float bH = b_hh[2 * NH + c];

  const bf16* hb_cur = hbf0;
  bf16* hb_nxt = hbf1;

  for (int t = 0; t < NT - 1; ++t) {
    const bf16* xrow0 = &xbf[((size_t)t * NB + mbase + ln15) * NH + k0 + q8];
    const bf16* xrow1 = xrow0 + 16 * NH;
    const bf16* hrow0 = &hb_cur[(size_t)(mbase + ln15) * NH + k0 + q8];
    const bf16* hrow1 = hrow0 + 16 * NH;

    f32x4 aR0 = {0,0,0,0}, aR1 = {0,0,0,0}, aZ0 = {0,0,0,0}, aZ1 = {0,0,0,0};
    f32x4 aNI0 = {0,0,0,0}, aNI1 = {0,0,0,0}, aNH0 = {0,0,0,0}, aNH1 = {0,0,0,0};
#pragma unroll
    for (int kc = 0; kc < 256; kc += 32) {
      const bf16x8 ax0 = *(const bf16x8*)(xrow0 + kc);
      const bf16x8 ax1 = *(const bf16x8*)(xrow1 + kc);
      const bf16x8 ah0 = *(const bf16x8*)(hrow0 + kc);
      const bf16x8 ah1 = *(const bf16x8*)(hrow1 + kc);
      const int kk = k0 + kc + q8;
      const bf16x8 biR = *(const bf16x8*)&Wi[ln15][kk];
      const bf16x8 bhR = *(const bf16x8*)&Wh[ln15][kk];
      const bf16x8 biZ = *(const bf16x8*)&Wi[16 + ln15][kk];
      const bf16x8 bhZ = *(const bf16x8*)&Wh[16 + ln15][kk];
      const bf16x8 biN = *(const bf16x8*)&Wi[32 + ln15][kk];
      const bf16x8 bhN = *(const bf16x8*)&Wh[32 + ln15][kk];
      aR0 = MFMA_BF16(ax0, biR, aR0, 0, 0, 0);
      aR1 = MFMA_BF16(ax1, biR, aR1, 0, 0, 0);
      aZ0 = MFMA_BF16(ax0, biZ, aZ0, 0, 0, 0);
      aZ1 = MFMA_BF16(ax1, biZ, aZ1, 0, 0, 0);
      aNI0 = MFMA_BF16(ax0, biN, aNI0, 0, 0, 0);
      aNI1 = MFMA_BF16(ax1, biN, aNI1, 0, 0, 0);
      aR0 = MFMA_BF16(ah0, bhR, aR0, 0, 0, 0);
      aR1 = MFMA_BF16(ah1, bhR, aR1, 0, 0, 0);
      aZ0 = MFMA_BF16(ah0, bhZ, aZ0, 0, 0, 0);
      aZ1 = MFMA_BF16(ah1, bhZ, aZ1, 0, 0, 0);
      aNH0 = MFMA_BF16(ah0, bhN, aNH0, 0, 0, 0);
      aNH1 = MFMA_BF16(ah1, bhN, aNH1, 0, 0, 0);
    }

    // ---- k-half reduction via LDS ----
    if (kw == 1) {
      *(f32x4*)&red[0][mw][lane][0] = aR0;
      *(f32x4*)&red[1][mw][lane][0] = aR1;
      *(f32x4*)&red[2][mw][lane][0] = aZ0;
      *(f32x4*)&red[3][mw][lane][0] = aZ1;
      *(f32x4*)&red[4][mw][lane][0] = aNI0;
      *(f32x4*)&red[5][mw][lane][0] = aNI1;
      *(f32x4*)&red[6][mw][lane][0] = aNH0;
      *(f32x4*)&red[7][mw][lane][0] = aNH1;
    }
    __syncthreads();
    if (kw == 0) {
      aR0 += *(const f32x4*)&red[0][mw][lane][0];
      aR1 += *(const f32x4*)&red[1][mw][lane][0];
      aZ0 += *(const f32x4*)&red[2][mw][lane][0];
      aZ1 += *(const f32x4*)&red[3][mw][lane][0];
      aNI0 += *(const f32x4*)&red[4][mw][lane][0];
      aNI1 += *(const f32x4*)&red[5][mw][lane][0];
      aNH0 += *(const f32x4*)&red[6][mw][lane][0];
      aNH1 += *(const f32x4*)&red[7][mw][lane][0];

      // ---- epilogue: gates + masked update, 8 rows per lane ----
      const int r4 = (lane >> 4) * 4;
#pragma unroll
      for (int sub = 0; sub < 2; ++sub) {
        const f32x4 vR = sub ? aR1 : aR0;
        const f32x4 vZ = sub ? aZ1 : aZ0;
        const f32x4 vNI = sub ? aNI1 : aNI0;
        const f32x4 vNH = sub ? aNH1 : aNH0;
        const int ms = mbase + sub * 16 + r4;
        const int4 mk = *(const int4*)&mask_T[t * NB + ms];
        const int mks[4] = {mk.x, mk.y, mk.z, mk.w};
#pragma unroll
        for (int i = 0; i < 4; ++i) {
          const int m = ms + i;
          const float hp = hstates[((size_t)t * NB + m) * NH + c];
          const float r = sigmoid_f(vR[i] + bR);
          const float z = sigmoid_f(vZ[i] + bZ);
          const float n = tanh_f(vNI[i] + bI + r * (vNH[i] + bH));
          const float o = mks[i] ? ((1.0f - z) * n + z * hp) : hp;
          hstates[((size_t)(t + 1) * NB + m) * NH + c] = o;
          hb_nxt[(size_t)m * NH + c] = (bf16)o;
        }
      }
    }

    // ---- b-tile barrier (32 blocks), monotone counter ----
    __syncthreads();
    if (t < NT - 2) {  // no barrier needed after the last step
      if (tid == 0) {
        __threadfence();                     // release: drain + flush
        atomicAdd(&cnt[btile], 1);           // device-scope
        const int target = 32 * (t + 1);
        int guard = 0;
        while (__hip_atomic_load(&cnt[btile], __ATOMIC_RELAXED,
                                 __HIP_MEMORY_SCOPE_AGENT) < target) {
          __builtin_amdgcn_s_sleep(2);
          if (++guard > (1 << 22)) break;    // safety: never hang the device
        }
        __threadfence();                     // acquire: invalidate caches
      }
      __syncthreads();
      __threadfence_block();
    }

    const bf16* tmp = hb_cur; hb_cur = hb_nxt; hb_nxt = (bf16*)tmp;
  }
}

// ---------------- all LN emits in one pass ----------------------------------
__global__ void ln_all_kernel(const float* __restrict__ hs,  // [T][B][H]
                              const float* __restrict__ lnw,
                              const float* __restrict__ lnb,
                              float* __restrict__ out) {  // [B][T][H]
  const int r = blockIdx.x;  // t*NB + b
  const int t = r >> 10, b = r & (NB - 1);
  const int i = threadIdx.x * 2;
  const float2 hv = *(const float2*)&hs[(size_t)r * NH + i];
  float mean, rstd;
  ln_stats(hv.x + hv.y, hv.x * hv.x + hv.y * hv.y, mean, rstd);
  const float2 lw = *(const float2*)&lnw[i];
  const float2 lb = *(const float2*)&lnb[i];
  float2 o;
  o.x = (hv.x - mean) * rstd * lw.x + lb.x;
  o.y = (hv.y - mean) * rstd * lw.y + lb.y;
  *(float2*)&out[((size_t)b * NT + t) * NH + i] = o;
}

// ---------------- host-side launch ------------------------------------------
extern "C" void kernel_launch(void* const* d_in, const int* in_sizes, int n_in,
                              void* d_out, int out_size, void* d_ws, size_t ws_size,
                              hipStream_t stream) {
  const int*   actions      = (const int*)d_in[0];
  const float* edge_tokens  = (const float*)d_in[1];
  const int*   stop_indices = (const int*)d_in[2];
  const float* question     = (const float*)d_in[3];
  const float* node_tokens  = (const float*)d_in[4];
  const int*   start_locals = (const int*)d_in[5];
  const int*   start_ptr    = (const int*)d_in[6];
  const float* w_ih         = (const float*)d_in[7];
  const float* w_hh         = (const float*)d_in[8];
  const float* b_ih         = (const float*)d_in[9];
  const float* b_hh         = (const float*)d_in[10];
  const float* ln_w         = (const float*)d_in[11];
  const float* ln_b         = (const float*)d_in[12];
  float* out = (float*)d_out;

  // ws layout (~205 MB)
  bf16* Wihbf = (bf16*)d_ws;
  bf16* Whhbf = Wihbf + (size_t)3 * NH * NH;
  bf16* Xbf   = Whhbf + (size_t)3 * NH * NH;
  float* hstates = (float*)(Xbf + (size_t)NB * NT * NH);
  bf16* Hb0 = (bf16*)(hstates + (size_t)NT * NB * NH);
  bf16* Hb1 = Hb0 + (size_t)NB * NH;
  int* mask_T = (int*)(Hb1 + (size_t)NB * NH);
  int* cnt = mask_T + NT * NB;

  hipMemsetAsync(cnt, 0, 8 * sizeof(int), stream);
  active_kernel<<<NB / 256, 256, 0, stream>>>(actions, stop_indices, mask_T);
  wcvt_kernel<<<(3 * NH * NH) / (256 * 4), 256, 0, stream>>>(w_ih, w_hh, Wihbf, Whhbf);
  xall_kernel<<<NB * NT, 256, 0, stream>>>(actions, edge_tokens, Xbf);
  h0_kernel<<<NB, 256, 0, stream>>>(question, node_tokens, start_locals, start_ptr,
                                    ln_w, ln_b, hstates, Hb0);

  void* kargs[] = {(void*)&hstates, (void*)&Hb0, (void*)&Hb1, (void*)&Xbf,
                   (void*)&Wihbf, (void*)&Whhbf, (void*)&b_ih, (void*)&b_hh,
                   (void*)&mask_T, (void*)&cnt};
  hipLaunchCooperativeKernel((const void*)pers_kernel, dim3(256), dim3(512),
                             kargs, 0, stream);

  ln_all_kernel<<<NB * NT, 256, 0, stream>>>(hstates, ln_w, ln_b, out);
}